// Round 1
// baseline (186.693 us; speedup 1.0000x reference)
//
#include <hip/hip_runtime.h>

// AI4Burgers: Lu = 0.5*conv3x3(u,w1) - u_vel*conv3x3(u,w2) - u_vel*conv3x3(u,w3)
// replicate pad, B=16, H=W=1024, fp32.
//
// R7 (prev): single-wave register-burst blocks, waves_per_eu(1,2). 62us/dispatch,
// 2.4 TB/s, Occupancy 17%, VALUBusy 9% -> latency-bound. Wave lifetime ~10.8us
// for ~0.5us of work; residency capped at ~2/EU by the attr max while VGPR=88
// would allow 5/EU.
//
// R8: (a) waves_per_eu(1,4) -- min stays 1 so the 512-VGPR budget still
// authorizes the burst (no sinking), max 4 doubles allowed residency;
// (b) halo columns reconstructed with __shfl_up/__shfl_down from the float4s
// already in registers + one 2-line uniform edge load per row, instead of 20
// stride-16B gathers that re-read the wave's own row segment (~3x L1/L2 read
// amplification on u, mostly L1-missing at 150KB/CU live set);
// (c) nontemporal float4 stores so the output stream doesn't evict the
// L3-resident inputs between bench iterations;
// (d) bijective XCD chunk swizzle (8192%8==0), yb-fastest decode so vertical
// halo neighbors land on the same XCD L2.

#define HH 1024
#define WW 1024
#define RPB 8                 // rows per wave
#define CPW 256               // columns per wave (64 lanes x 4 px)
#define NROW (RPB + 2)        // staged u rows (halo factor 1.25)

typedef float f32x4 __attribute__((ext_vector_type(4)));

__device__ __forceinline__ float rfl(float x) {
    union { float f; int i; } c; c.f = x;
    c.i = __builtin_amdgcn_readfirstlane(c.i);   // wave-uniform -> SGPR
    return c.f;
}

__global__ __attribute__((amdgpu_flat_work_group_size(64, 64),
                          amdgpu_waves_per_eu(1, 4)))
void burgers_stencil(
    const float* __restrict__ u,
    const float* __restrict__ uvel,
    const float* __restrict__ w1,
    const float* __restrict__ w2,
    const float* __restrict__ w3,
    float* __restrict__ out,
    int rowBlocks, int colBlocks)
{
    const int lane = threadIdx.x;

    // XCD chunk swizzle: each XCD gets a contiguous chunk of the grid.
    // Decode yb FASTEST so consecutive blocks in a chunk are vertical
    // neighbors (share 2 halo rows) on the same XCD L2.
    const int nwg = gridDim.x;
    int swz = blockIdx.x;
    if ((nwg & 7) == 0) {
        const int chunk = nwg >> 3;
        swz = (swz & 7) * chunk + (swz >> 3);
    }
    int rem = swz;
    const int yb = rem % rowBlocks; rem /= rowBlocks;
    const int xb = rem % colBlocks; rem /= colBlocks;
    const int b  = rem;

    const int y0 = yb * RPB;
    const int x0 = xb * CPW + lane * 4;

    const size_t img = (size_t)b * HH * WW;
    const float* ub  = u + img;

    // Weights -> SGPRs first (independent of the VMEM burst).
    float W1[9], W23[9];
#pragma unroll
    for (int i = 0; i < 9; ++i) {
        W1[i]  = rfl(w1[i]);
        W23[i] = rfl(w2[i] + w3[i]);    // fold: Lu = 0.5*c1 - vel*(c2+c3)
    }

    // Wave-uniform edge columns (clamp IS the replicate pad).
    const int xleft = xb * CPW;
    const int xeL = (xleft == 0) ? 0 : xleft - 1;            // left edge col
    const int xeR = (xleft + CPW >= WW) ? WW - 1 : xleft + CPW; // right edge col
    const int xe  = (lane & 1) ? xeR : xeL;  // lanes 0/1 carry the live values

    // ---- the burst: 28 independent VMEM ops, ~18KB in flight per wave ----
    float4 uv[NROW]; float ev[NROW];
#pragma unroll
    for (int i = 0; i < NROW; ++i) {
        int yr = y0 - 1 + i;
        yr = yr < 0 ? 0 : (yr > HH - 1 ? HH - 1 : yr);   // replicate pad rows
        const float* row = ub + (size_t)yr * WW;
        uv[i] = *(const float4*)(row + x0);
        ev[i] = row[xe];                 // 2 cache lines, uniform per lane-pair
    }
    float4 vv[RPB];
#pragma unroll
    for (int r = 0; r < RPB; ++r)
        vv[r] = *(const float4*)(uvel + img + (size_t)(y0 + r) * WW + x0);

    __builtin_amdgcn_sched_barrier(0);  // burst stays above the math

    // ---- halo reconstruct: cross-lane, zero memory traffic ----
    float ul[NROW], ur[NROW];
#pragma unroll
    for (int i = 0; i < NROW; ++i) {
        const float eL = __shfl(ev[i], 0);          // row[xeL]
        const float eR = __shfl(ev[i], 1);          // row[xeR]
        const float fl = __shfl_up(uv[i].w, 1);     // lane l-1's last px
        const float fr = __shfl_down(uv[i].x, 1);   // lane l+1's first px
        ul[i] = (lane == 0)  ? eL : fl;
        ur[i] = (lane == 63) ? eR : fr;
    }

    // ---- compute + store ----
#pragma unroll
    for (int r = 0; r < RPB; ++r) {
        float p[3][6];
#pragma unroll
        for (int rr = 0; rr < 3; ++rr) {
            const int i = r + rr;
            p[rr][0] = ul[i];
            p[rr][1] = uv[i].x; p[rr][2] = uv[i].y;
            p[rr][3] = uv[i].z; p[rr][4] = uv[i].w;
            p[rr][5] = ur[i];
        }
        const float vel[4] = {vv[r].x, vv[r].y, vv[r].z, vv[r].w};

        float o[4];
#pragma unroll
        for (int j = 0; j < 4; ++j) {
            float c1 = 0.f, c23 = 0.f;
#pragma unroll
            for (int rr = 0; rr < 3; ++rr) {
#pragma unroll
                for (int k = 0; k < 3; ++k) {
                    const float a = p[rr][j + k];
                    c1  = fmaf(W1[rr*3 + k],  a, c1);
                    c23 = fmaf(W23[rr*3 + k], a, c23);
                }
            }
            o[j] = fmaf(-vel[j], c23, 0.5f * c1);
        }
        f32x4 ov; ov.x = o[0]; ov.y = o[1]; ov.z = o[2]; ov.w = o[3];
        __builtin_nontemporal_store(
            ov, (f32x4*)(out + img + (size_t)(y0 + r) * WW + x0));
    }
}

extern "C" void kernel_launch(void* const* d_in, const int* in_sizes, int n_in,
                              void* d_out, int out_size, void* d_ws, size_t ws_size,
                              hipStream_t stream) {
    const float* u    = (const float*)d_in[0];
    const float* uvel = (const float*)d_in[1];
    const float* w1   = (const float*)d_in[2];
    const float* w2   = (const float*)d_in[3];
    const float* w3   = (const float*)d_in[4];
    float* out        = (float*)d_out;

    const int B = in_sizes[0] / (HH * WW);      // 16
    const int rowBlocks = HH / RPB;             // 128
    const int colBlocks = WW / CPW;             // 4
    dim3 grid(B * rowBlocks * colBlocks);       // 8192 single-wave blocks
    dim3 block(64);
    burgers_stencil<<<grid, block, 0, stream>>>(u, uvel, w1, w2, w3, out,
                                                rowBlocks, colBlocks);
}